// Round 8
// baseline (469.849 us; speedup 1.0000x reference)
//
#include <hip/hip_runtime.h>

#define N_NODES 50000
#define N_EDGES 800000
#define E2      850000        // N_EDGES + N_NODES (self loops)
#define NODE_IN 32
#define EDGE_IN 16
#define EMB     128
#define GAT_IN  160           // NODE_IN + EMB
#define NLAYER  2
#define NGRAPH  8
#define NB32    1563          // ceil(N_NODES/32)
#define NB64    782           // ceil(N_NODES/64) for MFMA dense kernels
#define EB      3321          // ceil(E2/256)
#define LOG2E   1.44269504088896340736f

// counting-sort geometry: bucket = dst>>9 (512 dsts/bucket), chunk = 4096 edges
#define NBUCK   98            // ceil(50000/512)
#define CHUNK   4096
#define NCHUNK  208           // ceil(E2/CHUNK)

// gwt (fragment-ordered bf16 W^T) offsets in shorts
#define GWT_SRC0 0
#define GWT_SRC1 20480
#define GWT_OUT  40960
#define GWT_G    57344
#define GWT_TOT  73728

typedef short bf16x8 __attribute__((ext_vector_type(8)));
typedef float f32x4 __attribute__((ext_vector_type(4)));

// bf16 pack/unpack without hip_bf16.h (round-to-nearest-even)
__device__ __forceinline__ unsigned int f2bf(float f) {
    unsigned int u = __float_as_uint(f);
    return (u + 0x7FFFu + ((u >> 16) & 1u)) >> 16;
}
__device__ __forceinline__ float bf2f(unsigned int h) {
    return __uint_as_float(h << 16);
}
__device__ __forceinline__ unsigned int pack2bf(float a, float b) {
    return f2bf(a) | (f2bf(b) << 16);
}

// ---------------------------------------------------------------------------
__global__ void zero_kernel(float* __restrict__ p, int n) {
    int i = blockIdx.x * blockDim.x + threadIdx.x;
    int stride = gridDim.x * blockDim.x;
    for (; i < n; i += stride) p[i] = 0.f;
}

// ---------------------------------------------------------------------------
// mega kernel: four independent phases in one launch.
// ---------------------------------------------------------------------------
__global__ __launch_bounds__(256) void mega_kernel(
    const int* __restrict__ edge_index, const float* __restrict__ edge_attr,
    const float* __restrict__ x, const float* __restrict__ W_in,
    const float* __restrict__ b_in,
    const float* __restrict__ Wsrc, const float* __restrict__ Wout,
    const float* __restrict__ Wg,
    int* __restrict__ hist, float* __restrict__ meta,
    unsigned int* __restrict__ h_bf, unsigned int* __restrict__ x_bf,
    unsigned short* __restrict__ gwt) {
    __shared__ float smem[32 * NODE_IN];  // 4 KB union
    int b = blockIdx.x, t = threadIdx.x;

    if (b < NCHUNK) {
        // ---- pass A: LDS histogram of dst>>9 for this 4096-edge chunk ----
        int* lh = (int*)smem;
        if (t < NBUCK) lh[t] = 0;
        __syncthreads();
        int c0 = b * CHUNK;
#pragma unroll
        for (int i = 0; i < CHUNK / 256; i++) {
            int e = c0 + i * 256 + t;
            if (e < E2) {
                int dst = (e < N_EDGES) ? edge_index[N_EDGES + e] : (e - N_EDGES);
                atomicAdd(&lh[dst >> 9], 1);
            }
        }
        __syncthreads();
        if (t < NBUCK) hist[t * NCHUNK + b] = lh[t];  // bucket-major
    } else if (b < NCHUNK + 512) {
        // ---- edge_attr mean ----
        if (t < 16) smem[t] = 0.f;
        __syncthreads();
        int gid = (b - NCHUNK) * 256 + t;
        int q = gid & 3;  // stride 512*256 divisible by 4 -> q constant
        const float4* ea4 = (const float4*)edge_attr;
        float4 s = make_float4(0.f, 0.f, 0.f, 0.f);
        for (int j = gid; j < N_EDGES * 4; j += 512 * 256) {
            float4 v = ea4[j];
            s.x += v.x; s.y += v.y; s.z += v.z; s.w += v.w;
        }
        atomicAdd(&smem[q * 4 + 0], s.x);
        atomicAdd(&smem[q * 4 + 1], s.y);
        atomicAdd(&smem[q * 4 + 2], s.z);
        atomicAdd(&smem[q * 4 + 3], s.w);
        __syncthreads();
        if (t < 16) atomicAdd(&meta[t], smem[t]);
    } else if (b < NCHUNK + 512 + NB32) {
        // ---- input projection: h = relu(x @ W_in + b) -> h_bf; also x_bf ----
        float (*inp)[NODE_IN] = (float (*)[NODE_IN])smem;
        int n0 = (b - NCHUNK - 512) * 32;
        for (int i = t; i < 32 * NODE_IN; i += 256) {
            int r = i >> 5, c = i & 31;
            int n = min(n0 + r, N_NODES - 1);
            inp[r][c] = x[(size_t)n * NODE_IN + c];
        }
        __syncthreads();
        for (int i = t; i < 32 * 16; i += 256) {
            int r = i >> 4, c = i & 15;
            int n = n0 + r;
            if (n < N_NODES) x_bf[(size_t)n * 16 + c] = pack2bf(inp[r][2 * c], inp[r][2 * c + 1]);
        }
        int wave = t >> 6, lane = t & 63;
        int c0 = lane * 2, c1 = c0 + 1;
        const float2* W2 = (const float2*)W_in;
        float acc[8][2];
#pragma unroll
        for (int j = 0; j < 8; j++) { acc[j][0] = b_in[c0]; acc[j][1] = b_in[c1]; }
#pragma unroll 2
        for (int k4 = 0; k4 < NODE_IN / 4; k4++) {
            float4 v[8];
#pragma unroll
            for (int j = 0; j < 8; j++) v[j] = *(const float4*)&inp[wave * 8 + j][k4 * 4];
#pragma unroll
            for (int kk = 0; kk < 4; kk++) {
                float2 w = W2[(k4 * 4 + kk) * 64 + lane];
#pragma unroll
                for (int j = 0; j < 8; j++) {
                    float vv = (&v[j].x)[kk];
                    acc[j][0] += vv * w.x;
                    acc[j][1] += vv * w.y;
                }
            }
        }
#pragma unroll
        for (int j = 0; j < 8; j++) {
            int n = n0 + wave * 8 + j;
            if (n < N_NODES)
                h_bf[(size_t)n * 64 + lane] = pack2bf(fmaxf(acc[j][0], 0.f), fmaxf(acc[j][1], 0.f));
        }
    } else {
        // ---- weight pre-transpose into bf16 fragment order ----
        int g = (b - NCHUNK - 512 - NB32) * 256 + t;
        const float* Wm;
        int base, gg;
        if (g < 5120) {        // W_src layer 0/1, K=160: 2560 groups each
            int l = g / 2560;
            gg = g - l * 2560;
            Wm = Wsrc + (size_t)l * GAT_IN * EMB;
            base = l * 20480;
        } else if (g < 7168) { // W_out, K=128: 2048 groups
            gg = g - 5120;
            Wm = Wout;
            base = GWT_OUT;
        } else {               // W_g
            gg = g - 7168;
            Wm = Wg;
            base = GWT_G;
        }
        int lane = gg & 63, tmp = gg >> 6;
        int nt = tmp & 7, kc = tmp >> 3;
        int quad = lane >> 4, l16 = lane & 15;
        int col = nt * 16 + l16, k0 = kc * 32 + quad * 8;
        unsigned int u[4];
#pragma unroll
        for (int j = 0; j < 4; j++)
            u[j] = pack2bf(Wm[(size_t)(k0 + 2 * j) * EMB + col],
                           Wm[(size_t)(k0 + 2 * j + 1) * EMB + col]);
        *(uint4*)(gwt + base + (size_t)gg * 8) = make_uint4(u[0], u[1], u[2], u[3]);
    }
}

// ---------------------------------------------------------------------------
// bucket_scan: per-bucket exclusive scan over the 208 chunk counts (in place)
// + bucket totals. grid = NBUCK.
// ---------------------------------------------------------------------------
__global__ __launch_bounds__(256) void bucket_scan_kernel(int* __restrict__ hist,
                                                          int* __restrict__ btot) {
    __shared__ int sm[256];
    int k = blockIdx.x, t = threadIdx.x;
    int v = (t < NCHUNK) ? hist[k * NCHUNK + t] : 0;
    sm[t] = v;
    __syncthreads();
#pragma unroll
    for (int d = 1; d < 256; d <<= 1) {
        int u = (t >= d) ? sm[t - d] : 0;
        __syncthreads();
        sm[t] += u;
        __syncthreads();
    }
    if (t < NCHUNK) hist[k * NCHUNK + t] = sm[t] - v;  // exclusive
    if (t == 255) btot[k] = sm[255];
}

// ---------------------------------------------------------------------------
// base_prep: scan bucket totals -> bucket_base; plus tiny prep math
// (mean finish + M matrix LOG2E-prescaled + loop_ae). 1 block.
// ---------------------------------------------------------------------------
__global__ __launch_bounds__(256) void base_prep_kernel(const int* __restrict__ btot,
                                                        int* __restrict__ bucket_base,
                                                        const float* __restrict__ W_edge,
                                                        const float* __restrict__ att_edge,
                                                        float* __restrict__ meta) {
    __shared__ int sm[256];
    int t = threadIdx.x;
    int v = (t < NBUCK) ? btot[t] : 0;
    sm[t] = v;
    __syncthreads();
#pragma unroll
    for (int d = 1; d < 256; d <<= 1) {
        int u = (t >= d) ? sm[t - d] : 0;
        __syncthreads();
        sm[t] += u;
        __syncthreads();
    }
    if (t < NBUCK) bucket_base[t] = sm[t] - v;  // exclusive
    if (t == NBUCK - 1) bucket_base[NBUCK] = sm[t];  // == E2

    // ---- prep: finish mean; M[l][k][h] (LOG2E-prescaled); loop_ae ----
    if (t < EDGE_IN) meta[t] = meta[t] * (1.0f / (float)N_EDGES);
    __syncthreads();
    if (t < 128) {
        int l = t >> 6, k = (t >> 2) & 15, h = t & 3;
        const float* w = W_edge + ((size_t)l * EDGE_IN + k) * EMB + h * 32;
        const float* a = att_edge + (size_t)l * EMB + h * 32;
        float acc = 0.f;
#pragma unroll
        for (int c = 0; c < 32; c++) acc += w[c] * a[c];
        meta[16 + (l * 16 + k) * 4 + h] = acc * LOG2E;
    }
    __syncthreads();
    if (t < 8) {
        int l = t >> 2, h = t & 3;
        float acc = 0.f;
#pragma unroll
        for (int k = 0; k < EDGE_IN; k++) acc += meta[k] * meta[16 + (l * 16 + k) * 4 + h];
        meta[144 + t] = acc;   // inherits LOG2E scale from M
    }
}

// ---------------------------------------------------------------------------
// scatter_bucket (pass B): re-read chunk edges, scatter {src|dstlow<<16, e}
// into pre-reserved disjoint bucket ranges via LDS cursors. No global atomics.
// ---------------------------------------------------------------------------
__global__ __launch_bounds__(256) void scatter_bucket_kernel(const int* __restrict__ edge_index,
                                                             const int* __restrict__ hist,
                                                             const int* __restrict__ bucket_base,
                                                             int2* __restrict__ brec) {
    __shared__ int cur[NBUCK];
    int b = blockIdx.x, t = threadIdx.x;
    if (t < NBUCK) cur[t] = bucket_base[t] + hist[t * NCHUNK + b];
    __syncthreads();
    int c0 = b * CHUNK;
#pragma unroll
    for (int i = 0; i < CHUNK / 256; i++) {
        int e = c0 + i * 256 + t;
        if (e < E2) {
            int src, dst;
            if (e < N_EDGES) {
                src = edge_index[e];
                dst = edge_index[N_EDGES + e];
            } else {
                src = dst = e - N_EDGES;
            }
            int pos = atomicAdd(&cur[dst >> 9], 1);
            brec[pos] = make_int2(src | ((dst & 511) << 16), e);
        }
    }
}

// ---------------------------------------------------------------------------
// local_sort (pass C): per bucket, LDS histogram + scan over dst&511, write
// off[] and scatter perm{src,e} in final CSR order (lightweight 8B records;
// the heavy ae computation streams separately at full GPU width).
// ---------------------------------------------------------------------------
__global__ __launch_bounds__(512) void local_sort_kernel(const int* __restrict__ bucket_base,
                                                         const int2* __restrict__ brec,
                                                         int* __restrict__ off,
                                                         int2* __restrict__ perm) {
    __shared__ int lh[512];
    __shared__ int sm[512];
    int k = blockIdx.x, t = threadIdx.x;
    int base = bucket_base[k], end = bucket_base[k + 1], cnt = end - base;
    lh[t] = 0;
    __syncthreads();
    for (int i = t; i < cnt; i += 512) {
        int2 r = brec[base + i];
        atomicAdd(&lh[(r.x >> 16) & 511], 1);
    }
    __syncthreads();
    int v = lh[t];
    sm[t] = v;
    __syncthreads();
#pragma unroll
    for (int d = 1; d < 512; d <<= 1) {
        int u = (t >= d) ? sm[t - d] : 0;
        __syncthreads();
        sm[t] += u;
        __syncthreads();
    }
    int excl = sm[t] - v;
    int dst = (k << 9) + t;
    if (dst < N_NODES) off[dst] = base + excl;
    if (k == NBUCK - 1 && t == 0) off[N_NODES] = E2;
    lh[t] = excl;  // cursor
    __syncthreads();
    for (int i = t; i < cnt; i += 512) {
        int2 r = brec[base + i];
        int dl = (r.x >> 16) & 511;
        int p = atomicAdd(&lh[dl], 1);
        perm[base + p] = make_int2(r.x & 0xFFFF, r.y);
    }
}

// ---------------------------------------------------------------------------
// compute_ae: stream positions in order; gather edge_attr[e] (one full 64B
// line per edge); write csr_src + csr_ae coalesced. ae carries LOG2E scale.
// ---------------------------------------------------------------------------
__global__ __launch_bounds__(256) void compute_ae_kernel(const int2* __restrict__ perm,
                                                         const float* __restrict__ edge_attr,
                                                         const float* __restrict__ meta,
                                                         int* __restrict__ csr_src,
                                                         float* __restrict__ csr_ae0,
                                                         float* __restrict__ csr_ae1) {
    __shared__ float Ml[128];
    __shared__ float loop_ae[8];
    int t = threadIdx.x;
    if (t < 128) Ml[t] = meta[16 + t];
    if (t < 8) loop_ae[t] = meta[144 + t];
    __syncthreads();
    int p = blockIdx.x * 256 + t;
    if (p >= E2) return;
    int2 pe = perm[p];
    int src = pe.x, e = pe.y;
    csr_src[p] = src;
    float ae[2][4];
    if (e < N_EDGES) {
        const float4* r4 = (const float4*)(edge_attr + (size_t)e * EDGE_IN);
#pragma unroll
        for (int l = 0; l < 2; l++)
#pragma unroll
            for (int hh = 0; hh < 4; hh++) ae[l][hh] = 0.f;
#pragma unroll
        for (int q = 0; q < 4; q++) {
            float4 v = r4[q];
#pragma unroll
            for (int l = 0; l < 2; l++) {
                const float* M = Ml + l * 64;
#pragma unroll
                for (int hh = 0; hh < 4; hh++) {
                    ae[l][hh] += v.x * M[(4 * q + 0) * 4 + hh] + v.y * M[(4 * q + 1) * 4 + hh] +
                                 v.z * M[(4 * q + 2) * 4 + hh] + v.w * M[(4 * q + 3) * 4 + hh];
                }
            }
        }
    } else {
#pragma unroll
        for (int l = 0; l < 2; l++)
#pragma unroll
            for (int hh = 0; hh < 4; hh++) ae[l][hh] = loop_ae[l * 4 + hh];
    }
    *(float4*)(csr_ae0 + (size_t)p * 4) = make_float4(ae[0][0], ae[0][1], ae[0][2], ae[0][3]);
    *(float4*)(csr_ae1 + (size_t)p * 4) = make_float4(ae[1][0], ae[1][1], ae[1][2], ae[1][3]);
}

// ---------------------------------------------------------------------------
// MFMA dense kernel. MODE 0: xs/a_s/a_d producer (K=GAT_IN). MODE 3: combined
// tail — blocks [0,NB64) do the W_out+LN path (-> out_nodes), blocks
// [NB64,2*NB64) do the W_g+LN+graph-sum path. The graph sum uses NON-ATOMIC
// per-block partial writes (gpartA/gpartB + gids) reduced in graph_out —
// the former per-column atomicAdd storm (100K atomics on 64 cache lines)
// serialized at the fabric and was the r7 tail regression.
// ---------------------------------------------------------------------------
template <int K, int MODE>
__global__ __launch_bounds__(256) void dense_mfma_kernel(
    const unsigned int* __restrict__ xbf, const unsigned int* __restrict__ hbf,
    const unsigned short* __restrict__ gwt, const float* __restrict__ bias,
    const float* __restrict__ v1, const float* __restrict__ v2,
    const int* __restrict__ batch,
    unsigned int* __restrict__ xs_out, float* __restrict__ a_s, float* __restrict__ a_d,
    float* __restrict__ out_nodes, float* __restrict__ gsum, float* __restrict__ gcnt,
    const float* __restrict__ bias2, const float* __restrict__ v1b,
    const float* __restrict__ v2b,
    float* __restrict__ gpartA, float* __restrict__ gpartB, int* __restrict__ gids) {
    constexpr int CLS = 132;
    __shared__ __align__(16) float cl[64 * CLS];            // 33 KB
    __shared__ float red[(MODE != 0) ? 64 : 1][8];
    __shared__ float locw[(MODE == 3) ? 4 : 1][2][EMB];
    __shared__ int bids[(MODE == 3) ? 64 : 1];

    int t = threadIdx.x;
    int mode = MODE;
    int blk = blockIdx.x;
    if (MODE == 3) {
        mode = (blockIdx.x < NB64) ? 1 : 2;
        blk = (mode == 1) ? blockIdx.x : blockIdx.x - NB64;
    }
    int n0 = blk * 64;
    const unsigned short* gw = gwt;
    const float* bias_ = bias;
    const float* v1_ = v1;
    const float* v2_ = v2;
    if (MODE == 3 && mode == 2) {
        gw = gwt + (GWT_G - GWT_OUT);
        bias_ = bias2; v1_ = v1b; v2_ = v2b;
    }
    if (MODE == 3 && mode == 2 && t < 64) bids[t] = batch[min(n0 + t, N_NODES - 1)];

    int wave = t >> 6, lane = t & 63;
    int quad = lane >> 4, l16 = lane & 15;
    int arow = min(n0 + wave * 16 + l16, N_NODES - 1);
    const bf16x8* B = (const bf16x8*)gw;
    f32x4 acc[8];
#pragma unroll
    for (int i = 0; i < 8; i++) acc[i] = (f32x4){0.f, 0.f, 0.f, 0.f};
#pragma unroll
    for (int kc = 0; kc < K / 32; kc++) {
        bf16x8 af;
        if (MODE == 0 && kc == 0) {
            af = *(const bf16x8*)(xbf + (size_t)arow * 16 + quad * 4);
        } else {
            int hk = ((MODE == 0) ? (kc - 1) : kc) * 16;  // UINT units (32 bf16/chunk)
            af = *(const bf16x8*)(hbf + (size_t)arow * 64 + hk + quad * 4);
        }
#pragma unroll
        for (int nt = 0; nt < 8; nt++) {
            bf16x8 bfv = B[(kc * 8 + nt) * 64 + lane];
            acc[nt] = __builtin_amdgcn_mfma_f32_16x16x32_bf16(af, bfv, acc[nt], 0, 0, 0);
        }
    }
#pragma unroll
    for (int nt = 0; nt < 8; nt++) {
#pragma unroll
        for (int i = 0; i < 4; i++) {
            int r = wave * 16 + quad * 4 + i;  // C: row = quad*4+reg, col = l16
            cl[r * CLS + nt * 16 + l16] = acc[nt][i];
        }
    }
    __syncthreads();

    // row-wise epilogue: thread t -> node r = t>>2, part p = t&3 (32 cols)
    int p = t & 3, r = t >> 2;
    int n = n0 + r;
    const float4* c4 = (const float4*)(cl + r * CLS + p * 32);

    if (MODE == 0) {
        const float4* s4 = (const float4*)(v1_ + p * 32);
        const float4* d4 = (const float4*)(v2_ + p * 32);
        if (n < N_NODES) {
            float s_ = 0.f, d_ = 0.f;
#pragma unroll
            for (int i = 0; i < 8; i++) {
                float4 cv = c4[i], sv = s4[i], dv = d4[i];
                s_ += cv.x * sv.x + cv.y * sv.y + cv.z * sv.z + cv.w * sv.w;
                d_ += cv.x * dv.x + cv.y * dv.y + cv.z * dv.z + cv.w * dv.w;
                uint2 pk = make_uint2(pack2bf(cv.x, cv.y), pack2bf(cv.z, cv.w));
                *(uint2*)(xs_out + (size_t)n * 64 + p * 16 + 2 * i) = pk;
            }
            a_s[(size_t)n * 4 + p] = s_ * LOG2E;
            a_d[(size_t)n * 4 + p] = d_ * LOG2E;
        }
    } else {
        const float4* b4 = (const float4*)(bias_ + p * 32);
        float vals[32];
        float s_ = 0.f, q_ = 0.f;
#pragma unroll
        for (int i = 0; i < 8; i++) {
            float4 cv = c4[i], bv = b4[i];
            float w0 = fmaxf(cv.x + bv.x, 0.f), w1 = fmaxf(cv.y + bv.y, 0.f);
            float w2 = fmaxf(cv.z + bv.z, 0.f), w3 = fmaxf(cv.w + bv.w, 0.f);
            vals[4 * i] = w0; vals[4 * i + 1] = w1; vals[4 * i + 2] = w2; vals[4 * i + 3] = w3;
            s_ += w0 + w1 + w2 + w3;
            q_ += w0 * w0 + w1 * w1 + w2 * w2 + w3 * w3;
        }
        red[r][p] = s_;
        red[r][4 + p] = q_;
        __syncthreads();
        float sm = red[r][0] + red[r][1] + red[r][2] + red[r][3];
        float sq = red[r][4] + red[r][5] + red[r][6] + red[r][7];
        float mean = sm * (1.f / EMB);
        float var = sq * (1.f / EMB) - mean * mean;
        float rstd = rsqrtf(var + 1e-5f);
        const float4* g4 = (const float4*)(v1_ + p * 32);
        const float4* be4 = (const float4*)(v2_ + p * 32);
#pragma unroll
        for (int i = 0; i < 8; i++) {
            float4 gv = g4[i], bv = be4[i];
            vals[4 * i]     = (vals[4 * i]     - mean) * rstd * gv.x + bv.x;
            vals[4 * i + 1] = (vals[4 * i + 1] - mean) * rstd * gv.y + bv.y;
            vals[4 * i + 2] = (vals[4 * i + 2] - mean) * rstd * gv.z + bv.z;
            vals[4 * i + 3] = (vals[4 * i + 3] - mean) * rstd * gv.w + bv.w;
        }
        if (mode == 1) {
            if (n < N_NODES) {
                float* op = out_nodes + (size_t)n * EMB + p * 32;
#pragma unroll
                for (int i = 0; i < 8; i++)
                    *(float4*)(op + 4 * i) = make_float4(vals[4 * i], vals[4 * i + 1],
                                                         vals[4 * i + 2], vals[4 * i + 3]);
            }
        } else {
            int nvalid = min(64, N_NODES - n0);
            int bmin = bids[0], bmax = bids[nvalid - 1];
            int bid = bids[r];
            bool inA = (bid == bmin) && (n < N_NODES);
            bool inB = (bid == bmax) && (bmax != bmin) && (n < N_NODES);
            if (n < N_NODES && bid != bmin && bid != bmax) {
                // interior graphs: rare (sorted batch, <=6 rows/graph boundary)
#pragma unroll
                for (int i = 0; i < 32; i++)
                    atomicAdd(&gsum[(size_t)bid * EMB + p * 32 + i], vals[i]);
            }
#pragma unroll
            for (int g = 0; g < 2; g++) {
                bool m = g ? inB : inA;
#pragma unroll
                for (int i = 0; i < 32; i++) {
                    float v = m ? vals[i] : 0.f;
                    v += __shfl_xor(v, 4, 64);
                    v += __shfl_xor(v, 8, 64);
                    v += __shfl_xor(v, 16, 64);
                    v += __shfl_xor(v, 32, 64);
                    if ((lane >> 2) == 0) locw[wave][g][(lane & 3) * 32 + i] = v;
                }
            }
            __syncthreads();
            if (t < 128) {
                float sA = locw[0][0][t] + locw[1][0][t] + locw[2][0][t] + locw[3][0][t];
                gpartA[(size_t)blk * EMB + t] = sA;
                if (bmax != bmin) {
                    float sB = locw[0][1][t] + locw[1][1][t] + locw[2][1][t] + locw[3][1][t];
                    gpartB[(size_t)blk * EMB + t] = sB;
                }
            } else if (t == 128) {
                gids[2 * blk] = bmin;
                gids[2 * blk + 1] = (bmax != bmin) ? bmax : -1;
            } else if (t == 255) {
                int cA = 0, cB = 0;
                for (int rr = 0; rr < nvalid; rr++) {
                    int bb = bids[rr];
                    if (bb == bmin) cA++;
                    else if (bb == bmax) cB++;
                    else atomicAdd(&gcnt[bb], 1.f);
                }
                atomicAdd(&gcnt[bmin], (float)cA);
                if (bmax != bmin && cB > 0) atomicAdd(&gcnt[bmax], (float)cB);
            }
        }
    }
}

// ---------------------------------------------------------------------------
// gather: wave per node; 16 lanes per edge, 4 edge-groups. Software-pipelined:
// next iteration's csr_src/csr_ae are prefetched while the current iteration's
// dependent a_s/xs gathers + accum run. Branchless leaky, exp2 on
// LOG2E-prescaled inputs.
// ---------------------------------------------------------------------------
__global__ __launch_bounds__(256) void gat_gather_kernel(const int* __restrict__ off,
                                                         const int* __restrict__ csr_src,
                                                         const float* __restrict__ csr_ae,
                                                         const unsigned int* __restrict__ xs,
                                                         const float* __restrict__ a_s,
                                                         const float* __restrict__ a_d,
                                                         const float* __restrict__ bias_l,
                                                         const float* __restrict__ gamma_l,
                                                         const float* __restrict__ beta_l,
                                                         unsigned int* __restrict__ h_bf) {
    int t = threadIdx.x, wave = t >> 6, lane = t & 63;
    int n = blockIdx.x * 4 + wave;  // grid = N/4 exactly
    int g = lane >> 4, l16 = lane & 15;
    int h = l16 >> 2;               // head for cols [l16*8, l16*8+8)
    float ad = a_d[n * 4 + h];      // LOG2E-prescaled
    int p0 = __builtin_amdgcn_readfirstlane(off[n]);
    int p1 = __builtin_amdgcn_readfirstlane(off[n + 1]);
    float den = 0.f;
    float acc[8];
#pragma unroll
    for (int j = 0; j < 8; j++) acc[j] = 0.f;

#define ACCUM8(X, EX)                                          \
    acc[0] += EX * __uint_as_float(X.x << 16);                 \
    acc[1] += EX * __uint_as_float(X.x & 0xFFFF0000u);         \
    acc[2] += EX * __uint_as_float(X.y << 16);                 \
    acc[3] += EX * __uint_as_float(X.y & 0xFFFF0000u);         \
    acc[4] += EX * __uint_as_float(X.z << 16);                 \
    acc[5] += EX * __uint_as_float(X.z & 0xFFFF0000u);         \
    acc[6] += EX * __uint_as_float(X.w << 16);                 \
    acc[7] += EX * __uint_as_float(X.w & 0xFFFF0000u);

    int niter = (p1 - p0) >> 3;   // full 8-edge iterations
    int pb = p0;
    int sA = 0, sB = 0;
    float aeA = 0.f, aeB = 0.f;
    if (niter > 0) {  // prologue prefetch
        int pA = pb + g, pB = pA + 4;
        sA = csr_src[pA];
        sB = csr_src[pB];
        aeA = csr_ae[pA * 4 + h];
        aeB = csr_ae[pB * 4 + h];
    }
    for (int it = 0; it < niter; it++) {
        int sA0 = sA, sB0 = sB;
        float aeA0 = aeA, aeB0 = aeB;
        pb += 8;
        if (it + 1 < niter) {  // prefetch next iteration (independent loads)
            int pA = pb + g, pB = pA + 4;
            sA = csr_src[pA];
            sB = csr_src[pB];
            aeA = csr_ae[pA * 4 + h];
            aeB = csr_ae[pB * 4 + h];
        }
        float asA = a_s[sA0 * 4 + h];
        float asB = a_s[sB0 * 4 + h];
        uint4 xA = *(const uint4*)(xs + (sA0 * 64 + l16 * 4));
        uint4 xB = *(const uint4*)(xs + (sB0 * 64 + l16 * 4));
        float alA = asA + ad + aeA0;
        alA = fmaxf(alA, 0.2f * alA);
        float exA = exp2f(alA);
        float alB = asB + ad + aeB0;
        alB = fmaxf(alB, 0.2f * alB);
        float exB = exp2f(alB);
        den += exA + exB;
        ACCUM8(xA, exA)
        ACCUM8(xB, exB)
    }
    // ---- masked tail (1..7 edges) ----
    if (pb < p1) {
        int plast = p1 - 1;
        int qA = pb + g, qB = pb + 4 + g;
        int pA = min(qA, plast), pB = min(qB, plast);
        int tsA = csr_src[pA], tsB = csr_src[pB];
        float aeA1 = csr_ae[pA * 4 + h];
        float aeB1 = csr_ae[pB * 4 + h];
        float asA = a_s[tsA * 4 + h];
        float asB = a_s[tsB * 4 + h];
        uint4 xA = *(const uint4*)(xs + (tsA * 64 + l16 * 4));
        uint4 xB = *(const uint4*)(xs + (tsB * 64 + l16 * 4));
        float alA = asA + ad + aeA1;
        alA = fmaxf(alA, 0.2f * alA);
        float exA = (qA <= plast) ? exp2f(alA) : 0.f;
        float alB = asB + ad + aeB1;
        alB = fmaxf(alB, 0.2f * alB);
        float exB = (qB <= plast) ? exp2f(alB) : 0.f;
        den += exA + exB;
        ACCUM8(xA, exA)
        ACCUM8(xB, exB)
    }
#undef ACCUM8

    // combine the 4 edge-groups (cols identical across groups)
#pragma unroll
    for (int j = 0; j < 8; j++) {
        acc[j] += __shfl_xor(acc[j], 16, 64);
        acc[j] += __shfl_xor(acc[j], 32, 64);
    }
    den += __shfl_xor(den, 16, 64);
    den += __shfl_xor(den, 32, 64);

    float dinv = 1.0f / (den + 1e-16f);
    int c0 = l16 * 8;
    const float4* b4 = (const float4*)(bias_l + c0);
    float4 bv0 = b4[0], bv1 = b4[1];
    float v[8];
    v[0] = acc[0] * dinv + bv0.x; v[1] = acc[1] * dinv + bv0.y;
    v[2] = acc[2] * dinv + bv0.z; v[3] = acc[3] * dinv + bv0.w;
    v[4] = acc[4] * dinv + bv1.x; v[5] = acc[5] * dinv + bv1.y;
    v[6] = acc[6] * dinv + bv1.z; v[7] = acc[7] * dinv + bv1.w;
    float sm = 0.f, sq = 0.f;
#pragma unroll
    for (int j = 0; j < 8; j++) { sm += v[j]; sq += v[j] * v[j]; }
#pragma unroll
    for (int o = 1; o <= 8; o <<= 1) {
        sm += __shfl_xor(sm, o, 64);
        sq += __shfl_xor(sq, o, 64);
    }
    float mean = sm * (1.f / EMB);
    float var = sq * (1.f / EMB) - mean * mean;
    float rstd = rsqrtf(var + 1e-5f);
    const float4* g4 = (const float4*)(gamma_l + c0);
    const float4* be4 = (const float4*)(beta_l + c0);
    float4 gv0 = g4[0], gv1 = g4[1], bev0 = be4[0], bev1 = be4[1];
    float y[8];
    y[0] = (v[0] - mean) * rstd * gv0.x + bev0.x;
    y[1] = (v[1] - mean) * rstd * gv0.y + bev0.y;
    y[2] = (v[2] - mean) * rstd * gv0.z + bev0.z;
    y[3] = (v[3] - mean) * rstd * gv0.w + bev0.w;
    y[4] = (v[4] - mean) * rstd * gv1.x + bev1.x;
    y[5] = (v[5] - mean) * rstd * gv1.y + bev1.y;
    y[6] = (v[6] - mean) * rstd * gv1.z + bev1.z;
    y[7] = (v[7] - mean) * rstd * gv1.w + bev1.w;
#pragma unroll
    for (int j = 0; j < 8; j++) y[j] = y[j] > 0.f ? y[j] : __expf(y[j]) - 1.f;  // elu
    if (g == 0) {
        uint4 o4;
        o4.x = pack2bf(y[0], y[1]);
        o4.y = pack2bf(y[2], y[3]);
        o4.z = pack2bf(y[4], y[5]);
        o4.w = pack2bf(y[6], y[7]);
        *(uint4*)(h_bf + (size_t)n * 64 + l16 * 4) = o4;
    }
}

// ---------------------------------------------------------------------------
// graph_out: reduce per-block partials (gpartA/gpartB keyed by gids) plus
// the interior-row atomics already in gsum; divide by counts. grid = 8 x 128.
// ---------------------------------------------------------------------------
__global__ __launch_bounds__(128) void graph_out_kernel(const float* __restrict__ gsum,
                                                        const float* __restrict__ gcnt,
                                                        const float* __restrict__ gpartA,
                                                        const float* __restrict__ gpartB,
                                                        const int* __restrict__ gids,
                                                        float* __restrict__ out) {
    int b = blockIdx.x;    // graph
    int c = threadIdx.x;   // column
    float s = gsum[(size_t)b * EMB + c];
    for (int k = 0; k < NB64; k++) {
        int2 id = ((const int2*)gids)[k];
        if (id.x == b) s += gpartA[(size_t)k * EMB + c];
        if (id.y == b) s += gpartB[(size_t)k * EMB + c];
    }
    float cnt = fmaxf(gcnt[b], 1.f);
    out[(size_t)N_NODES * EMB + (size_t)b * EMB + c] = s / cnt;
}

// ---------------------------------------------------------------------------
extern "C" void kernel_launch(void* const* d_in, const int* in_sizes, int n_in,
                              void* d_out, int out_size, void* d_ws, size_t ws_size,
                              hipStream_t stream) {
    (void)in_sizes; (void)n_in; (void)out_size; (void)ws_size;
    const float* x         = (const float*)d_in[0];
    const float* edge_attr = (const float*)d_in[1];
    const float* W_in      = (const float*)d_in[2];
    const float* b_in      = (const float*)d_in[3];
    const float* W_src     = (const float*)d_in[4];
    const float* W_edge    = (const float*)d_in[5];
    const float* att_src   = (const float*)d_in[6];
    const float* att_dst   = (const float*)d_in[7];
    const float* att_edge  = (const float*)d_in[8];
    const float* gat_bias  = (const float*)d_in[9];
    const float* ln_gamma  = (const float*)d_in[10];
    const float* ln_beta   = (const float*)d_in[11];
    const float* W_out     = (const float*)d_in[12];
    const float* b_out     = (const float*)d_in[13];
    const float* ln_og     = (const float*)d_in[14];
    const float* ln_ob     = (const float*)d_in[15];
    const float* W_g       = (const float*)d_in[16];
    const float* b_g       = (const float*)d_in[17];
    const float* g_gamma   = (const float*)d_in[18];
    const float* g_beta    = (const float*)d_in[19];
    const int* edge_index  = (const int*)d_in[20];
    const int* batch       = (const int*)d_in[21];
    float* out = (float*)d_out;

    float* ws              = (float*)d_ws;
    unsigned int* h_bf     = (unsigned int*)ws;               // N*64
    unsigned int* xs       = h_bf + (size_t)N_NODES * 64;     // N*64
    unsigned int* x_bf     = xs + (size_t)N_NODES * 64;       // N*16
    float* a_s             = (float*)(x_bf + (size_t)N_NODES * 16);  // N*4
    float* a_d             = a_s + (size_t)N_NODES * 4;       // N*4
    float* csr_ae          = a_d + (size_t)N_NODES * 4;       // 2*E2*4
    unsigned short* gwt    = (unsigned short*)(csr_ae + (size_t)2 * E2 * 4);  // 73728 shorts
    float* meta            = (float*)(gwt + GWT_TOT);         // 152
    float* gsum            = meta + 152;                      // 1024
    float* gcnt            = gsum + NGRAPH * EMB;             // 8
    int*   off             = (int*)(gcnt + NGRAPH);           // N+2 (padded even)
    int*   csr_src         = off + N_NODES + 2;               // E2
    int2*  brec            = (int2*)(csr_src + E2);           // E2 int2 (8B-aligned)
    int*   hist            = (int*)(brec + E2);               // NBUCK*NCHUNK
    int*   btot            = hist + NBUCK * NCHUNK;           // NBUCK
    int*   bucket_base     = btot + NBUCK;                    // NBUCK+2 (pad even)
    float* gpartA          = (float*)(bucket_base + NBUCK + 2);  // NB64*EMB
    float* gpartB          = gpartA + (size_t)NB64 * EMB;     // NB64*EMB
    int*   gids            = (int*)(gpartB + (size_t)NB64 * EMB);  // 2*NB64 (8B-aligned)
    // perm (int2[E2] = 6.8MB) aliases xs: xs is first written by dense layer 0,
    // which runs after compute_ae has consumed perm.
    int2*  perm            = (int2*)xs;
    // total ~17.3M words = 69.2 MB (fits workspace)

    zero_kernel<<<8, 256, 0, stream>>>(meta, 152 + NGRAPH * EMB + NGRAPH);
    mega_kernel<<<NCHUNK + 512 + NB32 + 36, 256, 0, stream>>>(
        edge_index, edge_attr, x, W_in, b_in, W_src, W_out, W_g,
        hist, meta, h_bf, x_bf, gwt);

    bucket_scan_kernel<<<NBUCK, 256, 0, stream>>>(hist, btot);
    base_prep_kernel<<<1, 256, 0, stream>>>(btot, bucket_base, W_edge, att_edge, meta);
    scatter_bucket_kernel<<<NCHUNK, 256, 0, stream>>>(edge_index, hist, bucket_base, brec);
    local_sort_kernel<<<NBUCK, 512, 0, stream>>>(bucket_base, brec, off, perm);
    compute_ae_kernel<<<EB, 256, 0, stream>>>(perm, edge_attr, meta,
                                              csr_src, csr_ae, csr_ae + (size_t)E2 * 4);

    for (int l = 0; l < NLAYER; l++) {
        dense_mfma_kernel<GAT_IN, 0><<<NB64, 256, 0, stream>>>(
            x_bf, h_bf, gwt + (l ? GWT_SRC1 : GWT_SRC0), nullptr,
            att_src + (size_t)l * EMB, att_dst + (size_t)l * EMB, nullptr,
            xs, a_s, a_d, nullptr, nullptr, nullptr, nullptr, nullptr, nullptr,
            nullptr, nullptr, nullptr);
        gat_gather_kernel<<<N_NODES / 4, 256, 0, stream>>>(
            off, csr_src, csr_ae + (size_t)l * E2 * 4, xs, a_s, a_d,
            gat_bias + (size_t)l * EMB, ln_gamma + (size_t)l * EMB,
            ln_beta + (size_t)l * EMB, h_bf);
    }

    dense_mfma_kernel<EMB, 3><<<2 * NB64, 256, 0, stream>>>(
        nullptr, h_bf, gwt + GWT_OUT, b_out, ln_og, ln_ob, batch,
        nullptr, nullptr, nullptr, out, gsum, gcnt, b_g, g_gamma, g_beta,
        gpartA, gpartB, gids);
    graph_out_kernel<<<NGRAPH, 128, 0, stream>>>(gsum, gcnt, gpartA, gpartB, gids, out);
}

// Round 9
// 400.003 us; speedup vs baseline: 1.1746x; 1.1746x over previous
//
#include <hip/hip_runtime.h>

#define N_NODES 50000
#define N_EDGES 800000
#define E2      850000        // N_EDGES + N_NODES (self loops)
#define NODE_IN 32
#define EDGE_IN 16
#define EMB     128
#define GAT_IN  160           // NODE_IN + EMB
#define NLAYER  2
#define NGRAPH  8
#define NB32    1563          // ceil(N_NODES/32)
#define NB64    782           // ceil(N_NODES/64) for MFMA dense kernels
#define EB      3321          // ceil(E2/256)
#define LOG2E   1.44269504088896340736f

// counting-sort geometry: bucket = dst>>9 (512 dsts/bucket), chunk = 4096 edges
#define NBUCK   98            // ceil(50000/512)
#define CHUNK   4096
#define NCHUNK  208           // ceil(E2/CHUNK)

// gwt (fragment-ordered bf16 W^T) offsets in shorts
#define GWT_SRC0 0
#define GWT_SRC1 20480
#define GWT_OUT  40960
#define GWT_G    57344
#define GWT_TOT  73728

typedef short bf16x8 __attribute__((ext_vector_type(8)));
typedef float f32x4 __attribute__((ext_vector_type(4)));

// bf16 pack/unpack without hip_bf16.h (round-to-nearest-even)
__device__ __forceinline__ unsigned int f2bf(float f) {
    unsigned int u = __float_as_uint(f);
    return (u + 0x7FFFu + ((u >> 16) & 1u)) >> 16;
}
__device__ __forceinline__ float bf2f(unsigned int h) {
    return __uint_as_float(h << 16);
}
__device__ __forceinline__ unsigned int pack2bf(float a, float b) {
    return f2bf(a) | (f2bf(b) << 16);
}

// ---------------------------------------------------------------------------
__global__ void zero_kernel(float* __restrict__ p, int n) {
    int i = blockIdx.x * blockDim.x + threadIdx.x;
    int stride = gridDim.x * blockDim.x;
    for (; i < n; i += stride) p[i] = 0.f;
}

// ---------------------------------------------------------------------------
// mega kernel: four independent phases in one launch.
// ---------------------------------------------------------------------------
__global__ __launch_bounds__(256) void mega_kernel(
    const int* __restrict__ edge_index, const float* __restrict__ edge_attr,
    const float* __restrict__ x, const float* __restrict__ W_in,
    const float* __restrict__ b_in,
    const float* __restrict__ Wsrc, const float* __restrict__ Wout,
    const float* __restrict__ Wg,
    int* __restrict__ hist, float* __restrict__ meta,
    unsigned int* __restrict__ h_bf, unsigned int* __restrict__ x_bf,
    unsigned short* __restrict__ gwt) {
    __shared__ float smem[32 * NODE_IN];  // 4 KB union
    int b = blockIdx.x, t = threadIdx.x;

    if (b < NCHUNK) {
        // ---- pass A: LDS histogram of dst>>9 for this 4096-edge chunk ----
        int* lh = (int*)smem;
        if (t < NBUCK) lh[t] = 0;
        __syncthreads();
        int c0 = b * CHUNK;
#pragma unroll
        for (int i = 0; i < CHUNK / 256; i++) {
            int e = c0 + i * 256 + t;
            if (e < E2) {
                int dst = (e < N_EDGES) ? edge_index[N_EDGES + e] : (e - N_EDGES);
                atomicAdd(&lh[dst >> 9], 1);
            }
        }
        __syncthreads();
        if (t < NBUCK) hist[t * NCHUNK + b] = lh[t];  // bucket-major
    } else if (b < NCHUNK + 512) {
        // ---- edge_attr mean ----
        if (t < 16) smem[t] = 0.f;
        __syncthreads();
        int gid = (b - NCHUNK) * 256 + t;
        int q = gid & 3;  // stride 512*256 divisible by 4 -> q constant
        const float4* ea4 = (const float4*)edge_attr;
        float4 s = make_float4(0.f, 0.f, 0.f, 0.f);
        for (int j = gid; j < N_EDGES * 4; j += 512 * 256) {
            float4 v = ea4[j];
            s.x += v.x; s.y += v.y; s.z += v.z; s.w += v.w;
        }
        atomicAdd(&smem[q * 4 + 0], s.x);
        atomicAdd(&smem[q * 4 + 1], s.y);
        atomicAdd(&smem[q * 4 + 2], s.z);
        atomicAdd(&smem[q * 4 + 3], s.w);
        __syncthreads();
        if (t < 16) atomicAdd(&meta[t], smem[t]);
    } else if (b < NCHUNK + 512 + NB32) {
        // ---- input projection: h = relu(x @ W_in + b) -> h_bf; also x_bf ----
        float (*inp)[NODE_IN] = (float (*)[NODE_IN])smem;
        int n0 = (b - NCHUNK - 512) * 32;
        for (int i = t; i < 32 * NODE_IN; i += 256) {
            int r = i >> 5, c = i & 31;
            int n = min(n0 + r, N_NODES - 1);
            inp[r][c] = x[(size_t)n * NODE_IN + c];
        }
        __syncthreads();
        for (int i = t; i < 32 * 16; i += 256) {
            int r = i >> 4, c = i & 15;
            int n = n0 + r;
            if (n < N_NODES) x_bf[(size_t)n * 16 + c] = pack2bf(inp[r][2 * c], inp[r][2 * c + 1]);
        }
        int wave = t >> 6, lane = t & 63;
        int c0 = lane * 2, c1 = c0 + 1;
        const float2* W2 = (const float2*)W_in;
        float acc[8][2];
#pragma unroll
        for (int j = 0; j < 8; j++) { acc[j][0] = b_in[c0]; acc[j][1] = b_in[c1]; }
#pragma unroll 2
        for (int k4 = 0; k4 < NODE_IN / 4; k4++) {
            float4 v[8];
#pragma unroll
            for (int j = 0; j < 8; j++) v[j] = *(const float4*)&inp[wave * 8 + j][k4 * 4];
#pragma unroll
            for (int kk = 0; kk < 4; kk++) {
                float2 w = W2[(k4 * 4 + kk) * 64 + lane];
#pragma unroll
                for (int j = 0; j < 8; j++) {
                    float vv = (&v[j].x)[kk];
                    acc[j][0] += vv * w.x;
                    acc[j][1] += vv * w.y;
                }
            }
        }
#pragma unroll
        for (int j = 0; j < 8; j++) {
            int n = n0 + wave * 8 + j;
            if (n < N_NODES)
                h_bf[(size_t)n * 64 + lane] = pack2bf(fmaxf(acc[j][0], 0.f), fmaxf(acc[j][1], 0.f));
        }
    } else {
        // ---- weight pre-transpose into bf16 fragment order ----
        int g = (b - NCHUNK - 512 - NB32) * 256 + t;
        const float* Wm;
        int base, gg;
        if (g < 5120) {        // W_src layer 0/1, K=160: 2560 groups each
            int l = g / 2560;
            gg = g - l * 2560;
            Wm = Wsrc + (size_t)l * GAT_IN * EMB;
            base = l * 20480;
        } else if (g < 7168) { // W_out, K=128: 2048 groups
            gg = g - 5120;
            Wm = Wout;
            base = GWT_OUT;
        } else {               // W_g
            gg = g - 7168;
            Wm = Wg;
            base = GWT_G;
        }
        int lane = gg & 63, tmp = gg >> 6;
        int nt = tmp & 7, kc = tmp >> 3;
        int quad = lane >> 4, l16 = lane & 15;
        int col = nt * 16 + l16, k0 = kc * 32 + quad * 8;
        unsigned int u[4];
#pragma unroll
        for (int j = 0; j < 4; j++)
            u[j] = pack2bf(Wm[(size_t)(k0 + 2 * j) * EMB + col],
                           Wm[(size_t)(k0 + 2 * j + 1) * EMB + col]);
        *(uint4*)(gwt + base + (size_t)gg * 8) = make_uint4(u[0], u[1], u[2], u[3]);
    }
}

// ---------------------------------------------------------------------------
// bucket_scan: per-bucket exclusive scan over the 208 chunk counts (in place)
// + bucket totals. grid = NBUCK.
// ---------------------------------------------------------------------------
__global__ __launch_bounds__(256) void bucket_scan_kernel(int* __restrict__ hist,
                                                          int* __restrict__ btot) {
    __shared__ int sm[256];
    int k = blockIdx.x, t = threadIdx.x;
    int v = (t < NCHUNK) ? hist[k * NCHUNK + t] : 0;
    sm[t] = v;
    __syncthreads();
#pragma unroll
    for (int d = 1; d < 256; d <<= 1) {
        int u = (t >= d) ? sm[t - d] : 0;
        __syncthreads();
        sm[t] += u;
        __syncthreads();
    }
    if (t < NCHUNK) hist[k * NCHUNK + t] = sm[t] - v;  // exclusive
    if (t == 255) btot[k] = sm[255];
}

// ---------------------------------------------------------------------------
// base_prep: scan bucket totals -> bucket_base; plus tiny prep math
// (mean finish + M matrix LOG2E-prescaled + loop_ae). 1 block.
// ---------------------------------------------------------------------------
__global__ __launch_bounds__(256) void base_prep_kernel(const int* __restrict__ btot,
                                                        int* __restrict__ bucket_base,
                                                        const float* __restrict__ W_edge,
                                                        const float* __restrict__ att_edge,
                                                        float* __restrict__ meta) {
    __shared__ int sm[256];
    int t = threadIdx.x;
    int v = (t < NBUCK) ? btot[t] : 0;
    sm[t] = v;
    __syncthreads();
#pragma unroll
    for (int d = 1; d < 256; d <<= 1) {
        int u = (t >= d) ? sm[t - d] : 0;
        __syncthreads();
        sm[t] += u;
        __syncthreads();
    }
    if (t < NBUCK) bucket_base[t] = sm[t] - v;  // exclusive
    if (t == NBUCK - 1) bucket_base[NBUCK] = sm[t];  // == E2

    // ---- prep: finish mean; M[l][k][h] (LOG2E-prescaled); loop_ae ----
    if (t < EDGE_IN) meta[t] = meta[t] * (1.0f / (float)N_EDGES);
    __syncthreads();
    if (t < 128) {
        int l = t >> 6, k = (t >> 2) & 15, h = t & 3;
        const float* w = W_edge + ((size_t)l * EDGE_IN + k) * EMB + h * 32;
        const float* a = att_edge + (size_t)l * EMB + h * 32;
        float acc = 0.f;
#pragma unroll
        for (int c = 0; c < 32; c++) acc += w[c] * a[c];
        meta[16 + (l * 16 + k) * 4 + h] = acc * LOG2E;
    }
    __syncthreads();
    if (t < 8) {
        int l = t >> 2, h = t & 3;
        float acc = 0.f;
#pragma unroll
        for (int k = 0; k < EDGE_IN; k++) acc += meta[k] * meta[16 + (l * 16 + k) * 4 + h];
        meta[144 + t] = acc;   // inherits LOG2E scale from M
    }
}

// ---------------------------------------------------------------------------
// scatter_bucket (pass B): re-read chunk edges, scatter {src|dstlow<<16, e}
// into pre-reserved disjoint bucket ranges via LDS cursors. No global atomics.
// ---------------------------------------------------------------------------
__global__ __launch_bounds__(256) void scatter_bucket_kernel(const int* __restrict__ edge_index,
                                                             const int* __restrict__ hist,
                                                             const int* __restrict__ bucket_base,
                                                             int2* __restrict__ brec) {
    __shared__ int cur[NBUCK];
    int b = blockIdx.x, t = threadIdx.x;
    if (t < NBUCK) cur[t] = bucket_base[t] + hist[t * NCHUNK + b];
    __syncthreads();
    int c0 = b * CHUNK;
#pragma unroll
    for (int i = 0; i < CHUNK / 256; i++) {
        int e = c0 + i * 256 + t;
        if (e < E2) {
            int src, dst;
            if (e < N_EDGES) {
                src = edge_index[e];
                dst = edge_index[N_EDGES + e];
            } else {
                src = dst = e - N_EDGES;
            }
            int pos = atomicAdd(&cur[dst >> 9], 1);
            brec[pos] = make_int2(src | ((dst & 511) << 16), e);
        }
    }
}

// ---------------------------------------------------------------------------
// local_sort (pass C): per bucket, LDS histogram + scan over dst&511, write
// off[] and scatter perm{src,e} in final CSR order (lightweight 8B records;
// the heavy ae computation streams separately at full GPU width).
// ---------------------------------------------------------------------------
__global__ __launch_bounds__(512) void local_sort_kernel(const int* __restrict__ bucket_base,
                                                         const int2* __restrict__ brec,
                                                         int* __restrict__ off,
                                                         int2* __restrict__ perm) {
    __shared__ int lh[512];
    __shared__ int sm[512];
    int k = blockIdx.x, t = threadIdx.x;
    int base = bucket_base[k], end = bucket_base[k + 1], cnt = end - base;
    lh[t] = 0;
    __syncthreads();
    for (int i = t; i < cnt; i += 512) {
        int2 r = brec[base + i];
        atomicAdd(&lh[(r.x >> 16) & 511], 1);
    }
    __syncthreads();
    int v = lh[t];
    sm[t] = v;
    __syncthreads();
#pragma unroll
    for (int d = 1; d < 512; d <<= 1) {
        int u = (t >= d) ? sm[t - d] : 0;
        __syncthreads();
        sm[t] += u;
        __syncthreads();
    }
    int excl = sm[t] - v;
    int dst = (k << 9) + t;
    if (dst < N_NODES) off[dst] = base + excl;
    if (k == NBUCK - 1 && t == 0) off[N_NODES] = E2;
    lh[t] = excl;  // cursor
    __syncthreads();
    for (int i = t; i < cnt; i += 512) {
        int2 r = brec[base + i];
        int dl = (r.x >> 16) & 511;
        int p = atomicAdd(&lh[dl], 1);
        perm[base + p] = make_int2(r.x & 0xFFFF, r.y);
    }
}

// ---------------------------------------------------------------------------
// compute_ae: stream positions in order; gather edge_attr[e] (one full 64B
// line per edge); write csr_src + csr_ae coalesced. ae carries LOG2E scale.
// ---------------------------------------------------------------------------
__global__ __launch_bounds__(256) void compute_ae_kernel(const int2* __restrict__ perm,
                                                         const float* __restrict__ edge_attr,
                                                         const float* __restrict__ meta,
                                                         int* __restrict__ csr_src,
                                                         float* __restrict__ csr_ae0,
                                                         float* __restrict__ csr_ae1) {
    __shared__ float Ml[128];
    __shared__ float loop_ae[8];
    int t = threadIdx.x;
    if (t < 128) Ml[t] = meta[16 + t];
    if (t < 8) loop_ae[t] = meta[144 + t];
    __syncthreads();
    int p = blockIdx.x * 256 + t;
    if (p >= E2) return;
    int2 pe = perm[p];
    int src = pe.x, e = pe.y;
    csr_src[p] = src;
    float ae[2][4];
    if (e < N_EDGES) {
        const float4* r4 = (const float4*)(edge_attr + (size_t)e * EDGE_IN);
#pragma unroll
        for (int l = 0; l < 2; l++)
#pragma unroll
            for (int hh = 0; hh < 4; hh++) ae[l][hh] = 0.f;
#pragma unroll
        for (int q = 0; q < 4; q++) {
            float4 v = r4[q];
#pragma unroll
            for (int l = 0; l < 2; l++) {
                const float* M = Ml + l * 64;
#pragma unroll
                for (int hh = 0; hh < 4; hh++) {
                    ae[l][hh] += v.x * M[(4 * q + 0) * 4 + hh] + v.y * M[(4 * q + 1) * 4 + hh] +
                                 v.z * M[(4 * q + 2) * 4 + hh] + v.w * M[(4 * q + 3) * 4 + hh];
                }
            }
        }
    } else {
#pragma unroll
        for (int l = 0; l < 2; l++)
#pragma unroll
            for (int hh = 0; hh < 4; hh++) ae[l][hh] = loop_ae[l * 4 + hh];
    }
    *(float4*)(csr_ae0 + (size_t)p * 4) = make_float4(ae[0][0], ae[0][1], ae[0][2], ae[0][3]);
    *(float4*)(csr_ae1 + (size_t)p * 4) = make_float4(ae[1][0], ae[1][1], ae[1][2], ae[1][3]);
}

// ---------------------------------------------------------------------------
// MFMA dense kernel. MODE 0: xs/a_s/a_d producer (K=GAT_IN). MODE 3: combined
// tail — blocks [0,NB64) do the W_out+LN path (-> out_nodes), blocks
// [NB64,2*NB64) do the W_g+LN+graph-sum path. Graph sums leave per-block
// partials (gpartA/gpartB + gids), reduced by graph_reduce_kernel.
// ---------------------------------------------------------------------------
template <int K, int MODE>
__global__ __launch_bounds__(256) void dense_mfma_kernel(
    const unsigned int* __restrict__ xbf, const unsigned int* __restrict__ hbf,
    const unsigned short* __restrict__ gwt, const float* __restrict__ bias,
    const float* __restrict__ v1, const float* __restrict__ v2,
    const int* __restrict__ batch,
    unsigned int* __restrict__ xs_out, float* __restrict__ a_s, float* __restrict__ a_d,
    float* __restrict__ out_nodes, float* __restrict__ gsum, float* __restrict__ gcnt,
    const float* __restrict__ bias2, const float* __restrict__ v1b,
    const float* __restrict__ v2b,
    float* __restrict__ gpartA, float* __restrict__ gpartB, int* __restrict__ gids) {
    constexpr int CLS = 132;
    __shared__ __align__(16) float cl[64 * CLS];            // 33 KB
    __shared__ float red[(MODE != 0) ? 64 : 1][8];
    __shared__ float locw[(MODE == 3) ? 4 : 1][2][EMB];
    __shared__ int bids[(MODE == 3) ? 64 : 1];

    int t = threadIdx.x;
    int mode = MODE;
    int blk = blockIdx.x;
    if (MODE == 3) {
        mode = (blockIdx.x < NB64) ? 1 : 2;
        blk = (mode == 1) ? blockIdx.x : blockIdx.x - NB64;
    }
    int n0 = blk * 64;
    const unsigned short* gw = gwt;
    const float* bias_ = bias;
    const float* v1_ = v1;
    const float* v2_ = v2;
    if (MODE == 3 && mode == 2) {
        gw = gwt + (GWT_G - GWT_OUT);
        bias_ = bias2; v1_ = v1b; v2_ = v2b;
    }
    if (MODE == 3 && mode == 2 && t < 64) bids[t] = batch[min(n0 + t, N_NODES - 1)];

    int wave = t >> 6, lane = t & 63;
    int quad = lane >> 4, l16 = lane & 15;
    int arow = min(n0 + wave * 16 + l16, N_NODES - 1);
    const bf16x8* B = (const bf16x8*)gw;
    f32x4 acc[8];
#pragma unroll
    for (int i = 0; i < 8; i++) acc[i] = (f32x4){0.f, 0.f, 0.f, 0.f};
#pragma unroll
    for (int kc = 0; kc < K / 32; kc++) {
        bf16x8 af;
        if (MODE == 0 && kc == 0) {
            af = *(const bf16x8*)(xbf + (size_t)arow * 16 + quad * 4);
        } else {
            int hk = ((MODE == 0) ? (kc - 1) : kc) * 16;  // UINT units (32 bf16/chunk)
            af = *(const bf16x8*)(hbf + (size_t)arow * 64 + hk + quad * 4);
        }
#pragma unroll
        for (int nt = 0; nt < 8; nt++) {
            bf16x8 bfv = B[(kc * 8 + nt) * 64 + lane];
            acc[nt] = __builtin_amdgcn_mfma_f32_16x16x32_bf16(af, bfv, acc[nt], 0, 0, 0);
        }
    }
#pragma unroll
    for (int nt = 0; nt < 8; nt++) {
#pragma unroll
        for (int i = 0; i < 4; i++) {
            int r = wave * 16 + quad * 4 + i;  // C: row = quad*4+reg, col = l16
            cl[r * CLS + nt * 16 + l16] = acc[nt][i];
        }
    }
    __syncthreads();

    // row-wise epilogue: thread t -> node r = t>>2, part p = t&3 (32 cols)
    int p = t & 3, r = t >> 2;
    int n = n0 + r;
    const float4* c4 = (const float4*)(cl + r * CLS + p * 32);

    if (MODE == 0) {
        const float4* s4 = (const float4*)(v1_ + p * 32);
        const float4* d4 = (const float4*)(v2_ + p * 32);
        if (n < N_NODES) {
            float s_ = 0.f, d_ = 0.f;
#pragma unroll
            for (int i = 0; i < 8; i++) {
                float4 cv = c4[i], sv = s4[i], dv = d4[i];
                s_ += cv.x * sv.x + cv.y * sv.y + cv.z * sv.z + cv.w * sv.w;
                d_ += cv.x * dv.x + cv.y * dv.y + cv.z * dv.z + cv.w * dv.w;
                uint2 pk = make_uint2(pack2bf(cv.x, cv.y), pack2bf(cv.z, cv.w));
                *(uint2*)(xs_out + (size_t)n * 64 + p * 16 + 2 * i) = pk;
            }
            a_s[(size_t)n * 4 + p] = s_ * LOG2E;
            a_d[(size_t)n * 4 + p] = d_ * LOG2E;
        }
    } else {
        const float4* b4 = (const float4*)(bias_ + p * 32);
        float vals[32];
        float s_ = 0.f, q_ = 0.f;
#pragma unroll
        for (int i = 0; i < 8; i++) {
            float4 cv = c4[i], bv = b4[i];
            float w0 = fmaxf(cv.x + bv.x, 0.f), w1 = fmaxf(cv.y + bv.y, 0.f);
            float w2 = fmaxf(cv.z + bv.z, 0.f), w3 = fmaxf(cv.w + bv.w, 0.f);
            vals[4 * i] = w0; vals[4 * i + 1] = w1; vals[4 * i + 2] = w2; vals[4 * i + 3] = w3;
            s_ += w0 + w1 + w2 + w3;
            q_ += w0 * w0 + w1 * w1 + w2 * w2 + w3 * w3;
        }
        red[r][p] = s_;
        red[r][4 + p] = q_;
        __syncthreads();
        float sm = red[r][0] + red[r][1] + red[r][2] + red[r][3];
        float sq = red[r][4] + red[r][5] + red[r][6] + red[r][7];
        float mean = sm * (1.f / EMB);
        float var = sq * (1.f / EMB) - mean * mean;
        float rstd = rsqrtf(var + 1e-5f);
        const float4* g4 = (const float4*)(v1_ + p * 32);
        const float4* be4 = (const float4*)(v2_ + p * 32);
#pragma unroll
        for (int i = 0; i < 8; i++) {
            float4 gv = g4[i], bv = be4[i];
            vals[4 * i]     = (vals[4 * i]     - mean) * rstd * gv.x + bv.x;
            vals[4 * i + 1] = (vals[4 * i + 1] - mean) * rstd * gv.y + bv.y;
            vals[4 * i + 2] = (vals[4 * i + 2] - mean) * rstd * gv.z + bv.z;
            vals[4 * i + 3] = (vals[4 * i + 3] - mean) * rstd * gv.w + bv.w;
        }
        if (mode == 1) {
            if (n < N_NODES) {
                float* op = out_nodes + (size_t)n * EMB + p * 32;
#pragma unroll
                for (int i = 0; i < 8; i++)
                    *(float4*)(op + 4 * i) = make_float4(vals[4 * i], vals[4 * i + 1],
                                                         vals[4 * i + 2], vals[4 * i + 3]);
            }
        } else {
            int nvalid = min(64, N_NODES - n0);
            int bmin = bids[0], bmax = bids[nvalid - 1];
            int bid = bids[r];
            bool inA = (bid == bmin) && (n < N_NODES);
            bool inB = (bid == bmax) && (bmax != bmin) && (n < N_NODES);
            if (n < N_NODES && bid != bmin && bid != bmax) {
                // interior graphs: rare (sorted batch, boundary rows only)
#pragma unroll
                for (int i = 0; i < 32; i++)
                    atomicAdd(&gsum[(size_t)bid * EMB + p * 32 + i], vals[i]);
            }
#pragma unroll
            for (int g = 0; g < 2; g++) {
                bool m = g ? inB : inA;
#pragma unroll
                for (int i = 0; i < 32; i++) {
                    float v = m ? vals[i] : 0.f;
                    v += __shfl_xor(v, 4, 64);
                    v += __shfl_xor(v, 8, 64);
                    v += __shfl_xor(v, 16, 64);
                    v += __shfl_xor(v, 32, 64);
                    if ((lane >> 2) == 0) locw[wave][g][(lane & 3) * 32 + i] = v;
                }
            }
            __syncthreads();
            if (t < 128) {
                float sA = locw[0][0][t] + locw[1][0][t] + locw[2][0][t] + locw[3][0][t];
                gpartA[(size_t)blk * EMB + t] = sA;
                if (bmax != bmin) {
                    float sB = locw[0][1][t] + locw[1][1][t] + locw[2][1][t] + locw[3][1][t];
                    gpartB[(size_t)blk * EMB + t] = sB;
                }
            } else if (t == 128) {
                gids[2 * blk] = bmin;
                gids[2 * blk + 1] = (bmax != bmin) ? bmax : -1;
            } else if (t == 255) {
                int cA = 0, cB = 0;
                for (int rr = 0; rr < nvalid; rr++) {
                    int bb = bids[rr];
                    if (bb == bmin) cA++;
                    else if (bb == bmax) cB++;
                    else atomicAdd(&gcnt[bb], 1.f);
                }
                atomicAdd(&gcnt[bmin], (float)cA);
                if (bmax != bmin && cB > 0) atomicAdd(&gcnt[bmax], (float)cB);
            }
        }
    }
}

// ---------------------------------------------------------------------------
// gather: wave per node; 16 lanes per edge, 4 edge-groups. Software-pipelined:
// next iteration's csr_src/csr_ae are prefetched while the current iteration's
// dependent a_s/xs gathers + accum run. Branchless leaky, exp2 on
// LOG2E-prescaled inputs.
// ---------------------------------------------------------------------------
__global__ __launch_bounds__(256) void gat_gather_kernel(const int* __restrict__ off,
                                                         const int* __restrict__ csr_src,
                                                         const float* __restrict__ csr_ae,
                                                         const unsigned int* __restrict__ xs,
                                                         const float* __restrict__ a_s,
                                                         const float* __restrict__ a_d,
                                                         const float* __restrict__ bias_l,
                                                         const float* __restrict__ gamma_l,
                                                         const float* __restrict__ beta_l,
                                                         unsigned int* __restrict__ h_bf) {
    int t = threadIdx.x, wave = t >> 6, lane = t & 63;
    int n = blockIdx.x * 4 + wave;  // grid = N/4 exactly
    int g = lane >> 4, l16 = lane & 15;
    int h = l16 >> 2;               // head for cols [l16*8, l16*8+8)
    float ad = a_d[n * 4 + h];      // LOG2E-prescaled
    int p0 = __builtin_amdgcn_readfirstlane(off[n]);
    int p1 = __builtin_amdgcn_readfirstlane(off[n + 1]);
    float den = 0.f;
    float acc[8];
#pragma unroll
    for (int j = 0; j < 8; j++) acc[j] = 0.f;

#define ACCUM8(X, EX)                                          \
    acc[0] += EX * __uint_as_float(X.x << 16);                 \
    acc[1] += EX * __uint_as_float(X.x & 0xFFFF0000u);         \
    acc[2] += EX * __uint_as_float(X.y << 16);                 \
    acc[3] += EX * __uint_as_float(X.y & 0xFFFF0000u);         \
    acc[4] += EX * __uint_as_float(X.z << 16);                 \
    acc[5] += EX * __uint_as_float(X.z & 0xFFFF0000u);         \
    acc[6] += EX * __uint_as_float(X.w << 16);                 \
    acc[7] += EX * __uint_as_float(X.w & 0xFFFF0000u);

    int niter = (p1 - p0) >> 3;   // full 8-edge iterations
    int pb = p0;
    int sA = 0, sB = 0;
    float aeA = 0.f, aeB = 0.f;
    if (niter > 0) {  // prologue prefetch
        int pA = pb + g, pB = pA + 4;
        sA = csr_src[pA];
        sB = csr_src[pB];
        aeA = csr_ae[pA * 4 + h];
        aeB = csr_ae[pB * 4 + h];
    }
    for (int it = 0; it < niter; it++) {
        int sA0 = sA, sB0 = sB;
        float aeA0 = aeA, aeB0 = aeB;
        pb += 8;
        if (it + 1 < niter) {  // prefetch next iteration (independent loads)
            int pA = pb + g, pB = pA + 4;
            sA = csr_src[pA];
            sB = csr_src[pB];
            aeA = csr_ae[pA * 4 + h];
            aeB = csr_ae[pB * 4 + h];
        }
        float asA = a_s[sA0 * 4 + h];
        float asB = a_s[sB0 * 4 + h];
        uint4 xA = *(const uint4*)(xs + (sA0 * 64 + l16 * 4));
        uint4 xB = *(const uint4*)(xs + (sB0 * 64 + l16 * 4));
        float alA = asA + ad + aeA0;
        alA = fmaxf(alA, 0.2f * alA);
        float exA = exp2f(alA);
        float alB = asB + ad + aeB0;
        alB = fmaxf(alB, 0.2f * alB);
        float exB = exp2f(alB);
        den += exA + exB;
        ACCUM8(xA, exA)
        ACCUM8(xB, exB)
    }
    // ---- masked tail (1..7 edges) ----
    if (pb < p1) {
        int plast = p1 - 1;
        int qA = pb + g, qB = pb + 4 + g;
        int pA = min(qA, plast), pB = min(qB, plast);
        int tsA = csr_src[pA], tsB = csr_src[pB];
        float aeA1 = csr_ae[pA * 4 + h];
        float aeB1 = csr_ae[pB * 4 + h];
        float asA = a_s[tsA * 4 + h];
        float asB = a_s[tsB * 4 + h];
        uint4 xA = *(const uint4*)(xs + (tsA * 64 + l16 * 4));
        uint4 xB = *(const uint4*)(xs + (tsB * 64 + l16 * 4));
        float alA = asA + ad + aeA1;
        alA = fmaxf(alA, 0.2f * alA);
        float exA = (qA <= plast) ? exp2f(alA) : 0.f;
        float alB = asB + ad + aeB1;
        alB = fmaxf(alB, 0.2f * alB);
        float exB = (qB <= plast) ? exp2f(alB) : 0.f;
        den += exA + exB;
        ACCUM8(xA, exA)
        ACCUM8(xB, exB)
    }
#undef ACCUM8

    // combine the 4 edge-groups (cols identical across groups)
#pragma unroll
    for (int j = 0; j < 8; j++) {
        acc[j] += __shfl_xor(acc[j], 16, 64);
        acc[j] += __shfl_xor(acc[j], 32, 64);
    }
    den += __shfl_xor(den, 16, 64);
    den += __shfl_xor(den, 32, 64);

    float dinv = 1.0f / (den + 1e-16f);
    int c0 = l16 * 8;
    const float4* b4 = (const float4*)(bias_l + c0);
    float4 bv0 = b4[0], bv1 = b4[1];
    float v[8];
    v[0] = acc[0] * dinv + bv0.x; v[1] = acc[1] * dinv + bv0.y;
    v[2] = acc[2] * dinv + bv0.z; v[3] = acc[3] * dinv + bv0.w;
    v[4] = acc[4] * dinv + bv1.x; v[5] = acc[5] * dinv + bv1.y;
    v[6] = acc[6] * dinv + bv1.z; v[7] = acc[7] * dinv + bv1.w;
    float sm = 0.f, sq = 0.f;
#pragma unroll
    for (int j = 0; j < 8; j++) { sm += v[j]; sq += v[j] * v[j]; }
#pragma unroll
    for (int o = 1; o <= 8; o <<= 1) {
        sm += __shfl_xor(sm, o, 64);
        sq += __shfl_xor(sq, o, 64);
    }
    float mean = sm * (1.f / EMB);
    float var = sq * (1.f / EMB) - mean * mean;
    float rstd = rsqrtf(var + 1e-5f);
    const float4* g4 = (const float4*)(gamma_l + c0);
    const float4* be4 = (const float4*)(beta_l + c0);
    float4 gv0 = g4[0], gv1 = g4[1], bev0 = be4[0], bev1 = be4[1];
    float y[8];
    y[0] = (v[0] - mean) * rstd * gv0.x + bev0.x;
    y[1] = (v[1] - mean) * rstd * gv0.y + bev0.y;
    y[2] = (v[2] - mean) * rstd * gv0.z + bev0.z;
    y[3] = (v[3] - mean) * rstd * gv0.w + bev0.w;
    y[4] = (v[4] - mean) * rstd * gv1.x + bev1.x;
    y[5] = (v[5] - mean) * rstd * gv1.y + bev1.y;
    y[6] = (v[6] - mean) * rstd * gv1.z + bev1.z;
    y[7] = (v[7] - mean) * rstd * gv1.w + bev1.w;
#pragma unroll
    for (int j = 0; j < 8; j++) y[j] = y[j] > 0.f ? y[j] : __expf(y[j]) - 1.f;  // elu
    if (g == 0) {
        uint4 o4;
        o4.x = pack2bf(y[0], y[1]);
        o4.y = pack2bf(y[2], y[3]);
        o4.z = pack2bf(y[4], y[5]);
        o4.w = pack2bf(y[6], y[7]);
        *(uint4*)(h_bf + (size_t)n * 64 + l16 * 4) = o4;
    }
}

// ---------------------------------------------------------------------------
// graph_reduce: parallel reduction of per-block partials. grid = NGRAPH*32
// blocks x 128 threads; each block scans ~25 of the NB64 partial rows for
// its graph and does one atomicAdd per column (<=32 contenders/address).
// Replaces the r8 serial 782-iteration loop at 0.15% occupancy (84 us).
// ---------------------------------------------------------------------------
#define KSLICE 25   // ceil(NB64 / 32)
__global__ __launch_bounds__(128) void graph_reduce_kernel(const float* __restrict__ gpartA,
                                                           const float* __restrict__ gpartB,
                                                           const int* __restrict__ gids,
                                                           float* __restrict__ gsum) {
    int b = blockIdx.x >> 5;        // graph
    int sl = blockIdx.x & 31;       // slice
    int c = threadIdx.x;            // column
    int k0 = sl * KSLICE, k1 = min(k0 + KSLICE, NB64);
    float s = 0.f;
    for (int k = k0; k < k1; k++) {
        int2 id = ((const int2*)gids)[k];
        if (id.x == b) s += gpartA[(size_t)k * EMB + c];
        if (id.y == b) s += gpartB[(size_t)k * EMB + c];
    }
    if (s != 0.f) atomicAdd(&gsum[(size_t)b * EMB + c], s);
}

__global__ __launch_bounds__(128) void graph_div_kernel(const float* __restrict__ gsum,
                                                        const float* __restrict__ gcnt,
                                                        float* __restrict__ out) {
    int i = blockIdx.x * 128 + threadIdx.x;  // grid = NGRAPH
    int b = i >> 7;
    float c = fmaxf(gcnt[b], 1.f);
    out[(size_t)N_NODES * EMB + i] = gsum[i] / c;
}

// ---------------------------------------------------------------------------
extern "C" void kernel_launch(void* const* d_in, const int* in_sizes, int n_in,
                              void* d_out, int out_size, void* d_ws, size_t ws_size,
                              hipStream_t stream) {
    (void)in_sizes; (void)n_in; (void)out_size; (void)ws_size;
    const float* x         = (const float*)d_in[0];
    const float* edge_attr = (const float*)d_in[1];
    const float* W_in      = (const float*)d_in[2];
    const float* b_in      = (const float*)d_in[3];
    const float* W_src     = (const float*)d_in[4];
    const float* W_edge    = (const float*)d_in[5];
    const float* att_src   = (const float*)d_in[6];
    const float* att_dst   = (const float*)d_in[7];
    const float* att_edge  = (const float*)d_in[8];
    const float* gat_bias  = (const float*)d_in[9];
    const float* ln_gamma  = (const float*)d_in[10];
    const float* ln_beta   = (const float*)d_in[11];
    const float* W_out     = (const float*)d_in[12];
    const float* b_out     = (const float*)d_in[13];
    const float* ln_og     = (const float*)d_in[14];
    const float* ln_ob     = (const float*)d_in[15];
    const float* W_g       = (const float*)d_in[16];
    const float* b_g       = (const float*)d_in[17];
    const float* g_gamma   = (const float*)d_in[18];
    const float* g_beta    = (const float*)d_in[19];
    const int* edge_index  = (const int*)d_in[20];
    const int* batch       = (const int*)d_in[21];
    float* out = (float*)d_out;

    float* ws              = (float*)d_ws;
    unsigned int* h_bf     = (unsigned int*)ws;               // N*64
    unsigned int* xs       = h_bf + (size_t)N_NODES * 64;     // N*64
    unsigned int* x_bf     = xs + (size_t)N_NODES * 64;       // N*16
    float* a_s             = (float*)(x_bf + (size_t)N_NODES * 16);  // N*4
    float* a_d             = a_s + (size_t)N_NODES * 4;       // N*4
    float* csr_ae          = a_d + (size_t)N_NODES * 4;       // 2*E2*4
    unsigned short* gwt    = (unsigned short*)(csr_ae + (size_t)2 * E2 * 4);  // 73728 shorts
    float* meta            = (float*)(gwt + GWT_TOT);         // 152
    float* gsum            = meta + 152;                      // 1024
    float* gcnt            = gsum + NGRAPH * EMB;             // 8
    int*   off             = (int*)(gcnt + NGRAPH);           // N+2 (padded even)
    int*   csr_src         = off + N_NODES + 2;               // E2
    int2*  brec            = (int2*)(csr_src + E2);           // E2 int2 (8B-aligned)
    int*   hist            = (int*)(brec + E2);               // NBUCK*NCHUNK
    int*   btot            = hist + NBUCK * NCHUNK;           // NBUCK
    int*   bucket_base     = btot + NBUCK;                    // NBUCK+2 (pad even)
    float* gpartA          = (float*)(bucket_base + NBUCK + 2);  // NB64*EMB
    float* gpartB          = gpartA + (size_t)NB64 * EMB;     // NB64*EMB
    int*   gids            = (int*)(gpartB + (size_t)NB64 * EMB);  // 2*NB64 (8B-aligned)
    // perm (int2[E2] = 6.8MB) aliases xs: xs is first written by dense layer 0,
    // which runs after compute_ae has consumed perm.
    int2*  perm            = (int2*)xs;
    // total ~17.3M words = 69.2 MB (fits workspace)

    zero_kernel<<<8, 256, 0, stream>>>(meta, 152 + NGRAPH * EMB + NGRAPH);
    mega_kernel<<<NCHUNK + 512 + NB32 + 36, 256, 0, stream>>>(
        edge_index, edge_attr, x, W_in, b_in, W_src, W_out, W_g,
        hist, meta, h_bf, x_bf, gwt);

    bucket_scan_kernel<<<NBUCK, 256, 0, stream>>>(hist, btot);
    base_prep_kernel<<<1, 256, 0, stream>>>(btot, bucket_base, W_edge, att_edge, meta);
    scatter_bucket_kernel<<<NCHUNK, 256, 0, stream>>>(edge_index, hist, bucket_base, brec);
    local_sort_kernel<<<NBUCK, 512, 0, stream>>>(bucket_base, brec, off, perm);
    compute_ae_kernel<<<EB, 256, 0, stream>>>(perm, edge_attr, meta,
                                              csr_src, csr_ae, csr_ae + (size_t)E2 * 4);

    for (int l = 0; l < NLAYER; l++) {
        dense_mfma_kernel<GAT_IN, 0><<<NB64, 256, 0, stream>>>(
            x_bf, h_bf, gwt + (l ? GWT_SRC1 : GWT_SRC0), nullptr,
            att_src + (size_t)l * EMB, att_dst + (size_t)l * EMB, nullptr,
            xs, a_s, a_d, nullptr, nullptr, nullptr, nullptr, nullptr, nullptr,
            nullptr, nullptr, nullptr);
        gat_gather_kernel<<<N_NODES / 4, 256, 0, stream>>>(
            off, csr_src, csr_ae + (size_t)l * E2 * 4, xs, a_s, a_d,
            gat_bias + (size_t)l * EMB, ln_gamma + (size_t)l * EMB,
            ln_beta + (size_t)l * EMB, h_bf);
    }

    dense_mfma_kernel<EMB, 3><<<2 * NB64, 256, 0, stream>>>(
        nullptr, h_bf, gwt + GWT_OUT, b_out, ln_og, ln_ob, batch,
        nullptr, nullptr, nullptr, out, gsum, gcnt, b_g, g_gamma, g_beta,
        gpartA, gpartB, gids);
    graph_reduce_kernel<<<NGRAPH * 32, 128, 0, stream>>>(gpartA, gpartB, gids, gsum);
    graph_div_kernel<<<NGRAPH, 128, 0, stream>>>(gsum, gcnt, out);
}